// Round 2
// baseline (145.657 us; speedup 1.0000x reference)
//
#include <hip/hip_runtime.h>

constexpr int SLN = 512, BSZ = 128, TAG = 32;
constexpr float INVLN2 = 1.4426950408889634f;
constexpr float LN2f = 0.6931471805599453f;

__device__ __forceinline__ float exp2_fast(float x) {
  return __builtin_amdgcn_exp2f(x);
}
__device__ __forceinline__ float log2_fast(float x) {
  return __builtin_amdgcn_logf(x);
}
// pull a[src_lane] where src_lane = byteidx>>2 ; per-lane index, no SGPR hazard
__device__ __forceinline__ float bperm(int byteidx, float v) {
  return __int_as_float(__builtin_amdgcn_ds_bpermute(byteidx, __float_as_int(v)));
}

// Block b < BSZ: forward scan (log-partition) for batch b -> ws[b]
// Block b >= BSZ: gold-path score for batch b-BSZ        -> ws[BSZ + b]
__global__ __launch_bounds__(64) void crf_fwd_kernel(
    const float* __restrict__ emission, const int* __restrict__ length,
    const int* __restrict__ target, const float* __restrict__ transition,
    const float* __restrict__ start_tr, const float* __restrict__ end_tr,
    float* __restrict__ ws) {
  const int blk = blockIdx.x;
  const int lane = threadIdx.x;

  if (blk < BSZ) {
    const int b = blk;
    const int len = length[b];      // in [2, 512]
    const int j = lane & 31;        // output column
    const int h = lane >> 5;        // k-half this lane accumulates
    const int bidx0 = h << 6;       // bpermute byte base = (16h)*4

    // E[k] = exp(transition[16h+k][j]) held in VGPRs
    float E[16];
#pragma unroll
    for (int k = 0; k < 16; ++k)
      E[k] = exp2_fast(transition[(16 * h + k) * TAG + j] * INVLN2);

    const float* emb = emission + (size_t)b * SLN * TAG + j;

    // alpha in linear base-2 domain, replicated across both wave halves
    float a = exp2_fast((start_tr[j] + emb[0]) * INVLN2);
    float base = 0.f;

    // double-buffered emission prefetch, 8 steps ahead
    float buf0[8], buf1[8];
#pragma unroll
    for (int u = 0; u < 8; ++u) buf0[u] = emb[(1 + u) * TAG];

    const int steps = len - 1;      // >= 1
    const int nfull = steps >> 3;
    const int tail = steps & 7;

    for (int kb = 0; kb < nfull; ++kb) {
      const int t0 = 1 + (kb << 3);
#pragma unroll
      for (int u = 0; u < 8; ++u) {
        int tp = t0 + 8 + u; tp = tp < SLN ? tp : SLN - 1;
        buf1[u] = emb[tp * TAG];
      }
#pragma unroll
      for (int u = 0; u < 8; ++u) {
        const float emf = exp2_fast(buf0[u] * INVLN2);   // off critical path
        float p0 = 0.f, p1 = 0.f;
#pragma unroll
        for (int k = 0; k < 16; k += 2) {
          p0 = fmaf(bperm(bidx0 + 4 * k,       a), E[k],     p0);
          p1 = fmaf(bperm(bidx0 + 4 * (k + 1), a), E[k + 1], p1);
        }
        float p = p0 + p1;
        p += __shfl_xor(p, 32, 64);   // combine halves; a replicated again
        a = p * emf;
      }
      // exact power-of-two renorm once per 8 steps
      {
        const unsigned ab = (unsigned)__builtin_amdgcn_readlane((int)__float_as_uint(a), 0);
        const int e = (int)((ab >> 23) & 255u) - 127;
        a *= __int_as_float((127 - e) << 23);   // * 2^-e, exact
        base += (float)e;
      }
#pragma unroll
      for (int u = 0; u < 8; ++u) buf0[u] = buf1[u];
    }

    if (tail) {
#pragma unroll
      for (int u = 0; u < 7; ++u) {
        const float emf = exp2_fast(buf0[u] * INVLN2);
        float p0 = 0.f, p1 = 0.f;
#pragma unroll
        for (int k = 0; k < 16; k += 2) {
          p0 = fmaf(bperm(bidx0 + 4 * k,       a), E[k],     p0);
          p1 = fmaf(bperm(bidx0 + 4 * (k + 1), a), E[k + 1], p1);
        }
        float p = p0 + p1;
        p += __shfl_xor(p, 32, 64);
        const float anew = p * emf;
        a = (u < tail) ? anew : a;    // wave-uniform mask, tail block only
      }
    }

    // log_partition = ln2 * (base + log2(sum_j a_j * exp(end_j)))
    float v = a * exp2_fast(end_tr[j] * INVLN2);
#pragma unroll
    for (int m = 16; m >= 1; m >>= 1) v += __shfl_xor(v, m, 64);
    if (lane == 0) ws[b] = LN2f * (base + log2_fast(v));

  } else {
    const int b = blk - BSZ;
    const int len = length[b];
    const int* tg = target + b * SLN;
    float s = 0.f;
#pragma unroll
    for (int k0 = 0; k0 < SLN; k0 += 64) {
      const int k = k0 + lane;
      if (k < len) {
        const int tk = tg[k];
        s += emission[((size_t)b * SLN + k) * TAG + tk];
        if (k >= 1) s += transition[tg[k - 1] * TAG + tk];
      }
    }
#pragma unroll
    for (int m = 32; m >= 1; m >>= 1) s += __shfl_xor(s, m, 64);
    if (lane == 0) {
      s += start_tr[tg[0]] + end_tr[tg[len - 1]];
      ws[BSZ + b] = s;
    }
  }
}

__global__ __launch_bounds__(64) void crf_reduce_kernel(const float* __restrict__ ws,
                                                        float* __restrict__ out) {
  const int lane = threadIdx.x;
  float v = (ws[lane] - ws[BSZ + lane]) + (ws[lane + 64] - ws[BSZ + lane + 64]);
#pragma unroll
  for (int m = 32; m >= 1; m >>= 1) v += __shfl_xor(v, m, 64);
  if (lane == 0) out[0] = v;
}

extern "C" void kernel_launch(void* const* d_in, const int* in_sizes, int n_in,
                              void* d_out, int out_size, void* d_ws, size_t ws_size,
                              hipStream_t stream) {
  const float* emission   = (const float*)d_in[0];
  const int*   length     = (const int*)d_in[1];
  const int*   target     = (const int*)d_in[2];
  const float* transition = (const float*)d_in[3];
  const float* start_tr   = (const float*)d_in[4];
  const float* end_tr     = (const float*)d_in[5];
  float* ws = (float*)d_ws;   // 256 floats: [0,128) logZ, [128,256) score

  crf_fwd_kernel<<<2 * BSZ, 64, 0, stream>>>(emission, length, target, transition,
                                             start_tr, end_tr, ws);
  crf_reduce_kernel<<<1, 64, 0, stream>>>(ws, (float*)d_out);
}

// Round 3
// 120.917 us; speedup vs baseline: 1.2046x; 1.2046x over previous
//
#include <hip/hip_runtime.h>

constexpr int SLN = 512, BSZ = 128, TAG = 32;
constexpr float INVLN2 = 1.4426950408889634f;
constexpr float LN2f = 0.6931471805599453f;

__device__ __forceinline__ float exp2_fast(float x) { return __builtin_amdgcn_exp2f(x); }
__device__ __forceinline__ float log2_fast(float x) { return __builtin_amdgcn_logf(x); }

// broadcast lane N of each 16-lane row to the whole row (DPP row_newbcast, VALU-only)
template<int N>
__device__ __forceinline__ float dpp_rowbcast(float v) {
  const int i = __float_as_int(v);
  return __int_as_float(__builtin_amdgcn_update_dpp(i, i, 0x150 + N, 0xF, 0xF, false));
}
__device__ __forceinline__ void pl16_swap(float& x, float& y) {
  asm("v_permlane16_swap_b32 %0, %1" : "+v"(x), "+v"(y));
}
__device__ __forceinline__ void pl32_swap(float& x, float& y) {
  asm("v_permlane32_swap_b32 %0, %1" : "+v"(x), "+v"(y));
}

struct AU { float a, u; };

// One CRF step. ucur layout: rows = [a0-15, a0-15, a16-31, a16-31].
// Lane (row r, idx i): j = i + 16*(r&1), k-half = r>>1.
// Returns a (j-layout, replicated across 32-halves) and next ucur.
__device__ __forceinline__ AU crf_step(float ucur, const float (&E)[16], float em, bool useQ) {
  const float emf = exp2_fast(em * INVLN2);
  float acc0 = 0.f, acc1 = 0.f;
#define KS(n) { const float bc = dpp_rowbcast<n>(ucur); \
                if ((n) & 1) acc1 = fmaf(bc, E[n], acc1); else acc0 = fmaf(bc, E[n], acc0); }
  KS(0) KS(1) KS(2) KS(3) KS(4) KS(5) KS(6) KS(7)
  KS(8) KS(9) KS(10) KS(11) KS(12) KS(13) KS(14) KS(15)
#undef KS
  const float p = acc0 + acc1;
  float pa = p, pb = p;
  pl32_swap(pa, pb);                 // sum(pa,pb) = lo-half + hi-half, any swap direction
  const float a = (pa + pb) * emf;   // full dot * emission, j-layout [J0,J1,J0,J1]
  float qa = a, qb = a;
  pl16_swap(qa, qb);                 // outputs {even-row-expand, odd-row-expand} (order probed)
  AU r; r.a = a; r.u = useQ ? qb : qa;
  return r;
}

// Block b < BSZ: forward scan (log-partition) for batch b -> ws[b]
// Block b >= BSZ: gold-path score for batch b-BSZ        -> ws[BSZ + b]
__global__ __launch_bounds__(64) void crf_fwd_kernel(
    const float* __restrict__ emission, const int* __restrict__ length,
    const int* __restrict__ target, const float* __restrict__ transition,
    const float* __restrict__ start_tr, const float* __restrict__ end_tr,
    float* __restrict__ ws) {
  const int blk = blockIdx.x;
  const int lane = threadIdx.x;

  if (blk < BSZ) {
    const int b = blk;
    const int len = length[b];                    // in [2, 512]
    const int j = (lane & 15) + 16 * ((lane >> 4) & 1);  // [J0,J1,J0,J1] rows
    const int kh = lane >> 5;                     // k-half per 32-half

    // one-time probe: which pl16_swap output is the even-row expand?
    int pv = lane, qv = lane;
    asm("v_permlane16_swap_b32 %0, %1" : "+v"(pv), "+v"(qv));
    const bool probe_even = (__builtin_amdgcn_readfirstlane(pv) == 0);
    const bool useQ = probe_even ? (lane >= 32) : (lane < 32);

    // E[n] = exp(transition[16*kh + n][j]), VGPR-resident
    float E[16];
#pragma unroll
    for (int n = 0; n < 16; ++n)
      E[n] = exp2_fast(transition[(16 * kh + n) * TAG + j] * INVLN2);

    const float* emb = emission + (size_t)b * SLN * TAG + j;

    // alpha in linear base-2 domain
    float a = exp2_fast((start_tr[j] + emb[0]) * INVLN2);
    float base = 0.f;
    float ucur;
    { float qa = a, qb = a; pl16_swap(qa, qb); ucur = useQ ? qb : qa; }

    // double-buffered emission prefetch, 8 steps ahead
    float buf0[8], buf1[8];
#pragma unroll
    for (int u = 0; u < 8; ++u) buf0[u] = emb[(1 + u) * TAG];

    const int steps = len - 1;                    // >= 1
    const int nfull = steps >> 3;
    const int tail = steps & 7;

    for (int kb = 0; kb < nfull; ++kb) {
      const int t0 = 1 + (kb << 3);
#pragma unroll
      for (int u = 0; u < 8; ++u) {
        int tp = t0 + 8 + u; tp = tp < SLN ? tp : SLN - 1;
        buf1[u] = emb[tp * TAG];
      }
#pragma unroll
      for (int u = 0; u < 8; ++u) {
        const AU r = crf_step(ucur, E, buf0[u], useQ);
        a = r.a; ucur = r.u;
      }
      // exact power-of-two renorm once per 8 steps (u lane0 = a[0])
      {
        const unsigned ab = (unsigned)__builtin_amdgcn_readfirstlane(__float_as_int(ucur));
        const int e = (int)((ab >> 23) & 255u) - 127;
        const float scale = __int_as_float((127 - e) << 23);  // * 2^-e, exact
        ucur *= scale; a *= scale;
        base += (float)e;
      }
#pragma unroll
      for (int u = 0; u < 8; ++u) buf0[u] = buf1[u];
    }

    if (tail) {
#pragma unroll
      for (int u = 0; u < 7; ++u) {
        const AU r = crf_step(ucur, E, buf0[u], useQ);
        const bool take = (u < tail);             // wave-uniform
        a = take ? r.a : a;
        ucur = take ? r.u : ucur;
      }
    }

    // log_partition = ln2 * (base + log2(0.5 * sum_lanes a_j * exp(end_j)))
    float v = a * exp2_fast(end_tr[j] * INVLN2);
#pragma unroll
    for (int m = 32; m >= 1; m >>= 1) v += __shfl_xor(v, m, 64);
    if (lane == 0) ws[b] = LN2f * (base + log2_fast(0.5f * v));

  } else {
    const int b = blk - BSZ;
    const int len = length[b];
    const int* tg = target + b * SLN;
    float s = 0.f;
#pragma unroll
    for (int k0 = 0; k0 < SLN; k0 += 64) {
      const int k = k0 + lane;
      if (k < len) {
        const int tk = tg[k];
        s += emission[((size_t)b * SLN + k) * TAG + tk];
        if (k >= 1) s += transition[tg[k - 1] * TAG + tk];
      }
    }
#pragma unroll
    for (int m = 32; m >= 1; m >>= 1) s += __shfl_xor(s, m, 64);
    if (lane == 0) {
      s += start_tr[tg[0]] + end_tr[tg[len - 1]];
      ws[BSZ + b] = s;
    }
  }
}

__global__ __launch_bounds__(64) void crf_reduce_kernel(const float* __restrict__ ws,
                                                        float* __restrict__ out) {
  const int lane = threadIdx.x;
  float v = (ws[lane] - ws[BSZ + lane]) + (ws[lane + 64] - ws[BSZ + lane + 64]);
#pragma unroll
  for (int m = 32; m >= 1; m >>= 1) v += __shfl_xor(v, m, 64);
  if (lane == 0) out[0] = v;
}

extern "C" void kernel_launch(void* const* d_in, const int* in_sizes, int n_in,
                              void* d_out, int out_size, void* d_ws, size_t ws_size,
                              hipStream_t stream) {
  const float* emission   = (const float*)d_in[0];
  const int*   length     = (const int*)d_in[1];
  const int*   target     = (const int*)d_in[2];
  const float* transition = (const float*)d_in[3];
  const float* start_tr   = (const float*)d_in[4];
  const float* end_tr     = (const float*)d_in[5];
  float* ws = (float*)d_ws;   // 256 floats: [0,128) logZ, [128,256) score

  crf_fwd_kernel<<<2 * BSZ, 64, 0, stream>>>(emission, length, target, transition,
                                             start_tr, end_tr, ws);
  crf_reduce_kernel<<<1, 64, 0, stream>>>(ws, (float*)d_out);
}